// Round 5
// baseline (624.062 us; speedup 1.0000x reference)
//
#include <hip/hip_runtime.h>
#include <math.h>

#define EPS 1e-6f
constexpr int N_ = 4, L_ = 4096, H_ = 16, D_ = 64;
constexpr int NH = N_ * H_;             // 64
constexpr int HD = H_ * D_;             // 1024 floats per (n,l) row
constexpr long NSTRIDE = (long)L_ * HD;
constexpr int SCHUNKS = 16;             // 256 s-rows per kv chunk

typedef __attribute__((ext_vector_type(8))) short short8;
typedef __attribute__((ext_vector_type(4))) float f32x4;

// Scratch device globals. ksum/qsum/qnr zeroed by k0 each call; everything
// else fully written before read each call (graph-replay safe).
__device__ float g_qsum[NH * D_];
__device__ float g_ksum[NH * D_];
__device__ float g_qnr[NH * D_];
__device__ float g_knc[NH * D_];
__device__ float g_kv[NH * D_ * D_];
__device__ float g_kvpart[(long)SCHUNKS * NH * D_ * D_];   // 16 MB
__device__ float g_kncpart[SCHUNKS * NH * D_];
__device__ float g_ssumpart[SCHUNKS * NH];

__device__ __forceinline__ float sigm(float x) {
    return 1.0f / (1.0f + __expf(-x));
}
__device__ __forceinline__ float4 sigm4(float4 x) {
    float4 r;
    r.x = sigm(x.x); r.y = sigm(x.y); r.z = sigm(x.z); r.w = sigm(x.w);
    return r;
}
// 16-lane group sum via DPP (full-rate VALU, no DS-pipe traffic).
// dpp_ctrl must be an immediate -> template parameter.
template <int CTRL>
__device__ __forceinline__ float dpp_add(float x) {
    int y = __builtin_amdgcn_update_dpp(0, __float_as_int(x), CTRL, 0xf, 0xf, true);
    return x + __int_as_float(y);
}
// After quad_perm xor1+xor2 the value is quad-uniform, so row_half_mirror
// and row_mirror complete the 16-lane butterfly.
__device__ __forceinline__ float red16(float p) {
    p = dpp_add<0xB1>(p);    // quad_perm [1,0,3,2]  (xor 1)
    p = dpp_add<0x4E>(p);    // quad_perm [2,3,0,1]  (xor 2)
    p = dpp_add<0x141>(p);   // row_half_mirror      (pairs quads 0-1, 2-3)
    p = dpp_add<0x140>(p);   // row_mirror           (pairs halves)
    return p;
}
// RNE round of fp32 bits to bf16, returned high-16-aligned
__device__ __forceinline__ unsigned rne_hi(unsigned xb) {
    return (xb + 0x7fffu + ((xb >> 16) & 1u)) & 0xffff0000u;
}
// split: x ~= h1 + h2 (each bf16), residual <= 2^-17 |x|
__device__ __forceinline__ uint2 split2(float x) {
    unsigned h1 = rne_hi(__float_as_uint(x));
    float r = x - __uint_as_float(h1);
    unsigned h2 = rne_hi(__float_as_uint(r));
    return make_uint2(h1, h2);
}
union U8 { unsigned u[4]; short8 s; };

// ---------------- k0: zero the three atomic accumulators (12 KB) ----------------
__global__ void k0_zero() {
    int i = blockIdx.x * 256 + threadIdx.x;    // 12 blocks -> 3072 threads
    float4 z = {0.f, 0.f, 0.f, 0.f};
    if (i < 1024) *(float4*)&g_ksum[i * 4] = z;
    else if (i < 2048) *(float4*)&g_qsum[(i - 1024) * 4] = z;
    else if (i < 3072) *(float4*)&g_qnr[(i - 2048) * 4] = z;
}

// ---------------- kA: ksum via direct atomics (8 loads in flight) ----------------
__global__ __launch_bounds__(256, 8) void kA_ksum(const float* __restrict__ k) {
    int t = threadIdx.x;
    long g0 = (long)blockIdx.x * 8;
    int n = (int)(g0 >> 12);                   // 8 | 4096 so n constant per block
    const float* p = k + g0 * HD + t * 4;
    float4 x[8];
#pragma unroll
    for (int r = 0; r < 8; ++r) x[r] = *(const float4*)(p + (long)r * HD);
    float ax = 0.f, ay = 0.f, az = 0.f, aw = 0.f;
#pragma unroll
    for (int r = 0; r < 8; ++r) {
        float4 s = sigm4(x[r]);
        ax += s.x; ay += s.y; az += s.z; aw += s.w;
    }
    float* d0 = g_ksum + n * 1024 + t * 4;
    atomicAdd(d0 + 0, ax);
    atomicAdd(d0 + 1, ay);
    atomicAdd(d0 + 2, az);
    atomicAdd(d0 + 3, aw);
}

// ---------------- kB: qsum AND qnr in one q pass (direct atomics) ----------------
__global__ __launch_bounds__(256, 8) void kB_q(const float* __restrict__ q) {
    int t = threadIdx.x;
    long g0 = (long)blockIdx.x * 8;
    int n = (int)(g0 >> 12);
    float4 bv = *(const float4*)(g_ksum + n * 1024 + t * 4);
    bv.x += EPS; bv.y += EPS; bv.z += EPS; bv.w += EPS;
    const float* p = q + g0 * HD + t * 4;
    float4 x[8];
#pragma unroll
    for (int r = 0; r < 8; ++r) x[r] = *(const float4*)(p + (long)r * HD);
    float sx = 0.f, sy = 0.f, sz = 0.f, sw = 0.f;
    float nx = 0.f, ny = 0.f, nz = 0.f, nw = 0.f;
#pragma unroll
    for (int r = 0; r < 8; ++r) {
        float4 s = sigm4(x[r]);
        sx += s.x; sy += s.y; sz += s.z; sw += s.w;
        float pd = (s.x + EPS) * bv.x + (s.y + EPS) * bv.y
                 + (s.z + EPS) * bv.z + (s.w + EPS) * bv.w;
        pd = red16(pd);                        // full 64-d dot for this row
        float inv = 1.0f / pd;                 // nr
        nx += s.x * inv; ny += s.y * inv; nz += s.z * inv; nw += s.w * inv;
    }
    float* ds = g_qsum + n * 1024 + t * 4;
    float* dn = g_qnr + n * 1024 + t * 4;
    atomicAdd(ds + 0, sx); atomicAdd(ds + 1, sy);
    atomicAdd(ds + 2, sz); atomicAdd(ds + 3, sw);
    atomicAdd(dn + 0, nx); atomicAdd(dn + 1, ny);
    atomicAdd(dn + 2, nz); atomicAdd(dn + 3, nw);
}

// ---------------- k4: fused nc+knc+cr+exp+ssum + split2-bf16 MFMA kv ---------
// Double-buffered LDS planes (1 barrier/step), prefetch issued at step top.
// LDS planes: u32 at [s-pair][col] = {lo16 = bf16(even s), hi16 = bf16(odd s)}
__global__ __launch_bounds__(256, 4) void k4_kv(const float* __restrict__ k,
                                                const float* __restrict__ v) {
    int nh = blockIdx.y, n = nh >> 4, h = nh & 15;
    int t = threadIdx.x, lane = t & 63, wv = t >> 6;
    __shared__ unsigned planes[2][4][16 * 66];   // [buf][kA,kB,vA,vB][s-pair*66+col]
    __shared__ float kncred[16 * 64];
    __shared__ float esb[256];
    int sp = t >> 4, c4 = t & 15;
    long nbase = (long)n * NSTRIDE + (long)h * D_;
    int s0blk = blockIdx.x * 256;
    float4 qn = *(const float4*)&g_qnr[nh * 64 + c4 * 4];
    qn.x += EPS; qn.y += EPS; qn.z += EPS; qn.w += EPS;
    float4 qs = *(const float4*)&g_qsum[nh * 64 + c4 * 4];
    qs.x += EPS; qs.y += EPS; qs.z += EPS; qs.w += EPS;

    f32x4 acc[4];
#pragma unroll
    for (int e = 0; e < 4; ++e) acc[e] = (f32x4){0.f, 0.f, 0.f, 0.f};
    int m = lane & 15, qd = lane >> 4;
    float esum = 0.f;
    float knx = 0.f, kny = 0.f, knz = 0.f, knw = 0.f;

    float4 ke, ko, ve, vo;
    {
        long gb = nbase + (long)(s0blk + 2 * sp) * HD + c4 * 4;
        ke = *(const float4*)&k[gb]; ko = *(const float4*)&k[gb + HD];
        ve = *(const float4*)&v[gb]; vo = *(const float4*)&v[gb + HD];
    }
    for (int st = 0; st < 8; ++st) {
        // ---- issue next subtile's loads FIRST (in flight across pack+bar+MFMA)
        float4 nke, nko, nve, nvo;
        if (st < 7) {
            long gb = nbase + (long)(s0blk + (st + 1) * 32 + 2 * sp) * HD + c4 * 4;
            nke = *(const float4*)&k[gb]; nko = *(const float4*)&k[gb + HD];
            nve = *(const float4*)&v[gb]; nvo = *(const float4*)&v[gb + HD];
        }
        // ---- sigm + nc/cr dots (DPP) + exp + knc + scale + pack
        float4 se = sigm4(ke), so = sigm4(ko);
        float pde = (se.x + EPS) * qn.x + (se.y + EPS) * qn.y
                  + (se.z + EPS) * qn.z + (se.w + EPS) * qn.w;
        float pdo = (so.x + EPS) * qn.x + (so.y + EPS) * qn.y
                  + (so.z + EPS) * qn.z + (so.w + EPS) * qn.w;
        float pne = (se.x + EPS) * qs.x + (se.y + EPS) * qs.y
                  + (se.z + EPS) * qs.z + (se.w + EPS) * qs.w;
        float pno = (so.x + EPS) * qs.x + (so.y + EPS) * qs.y
                  + (so.z + EPS) * qs.z + (so.w + EPS) * qs.w;
        pde = red16(pde); pdo = red16(pdo);
        pne = red16(pne); pno = red16(pno);
        float ee = __expf(pde), eo = __expf(pdo);
        if (c4 == 0) esum += ee + eo;
        float nce = 1.0f / pne, nco = 1.0f / pno;
        knx += se.x * nce + so.x * nco;
        kny += se.y * nce + so.y * nco;
        knz += se.z * nce + so.z * nco;
        knw += se.w * nce + so.w * nco;
        se.x *= ee; se.y *= ee; se.z *= ee; se.w *= ee;
        so.x *= eo; so.y *= eo; so.z *= eo; so.w *= eo;
        uint2 a0 = split2(se.x), a1_ = split2(se.y), a2_ = split2(se.z), a3_ = split2(se.w);
        uint2 b0 = split2(so.x), b1_ = split2(so.y), b2_ = split2(so.z), b3_ = split2(so.w);
        uint2 c0 = split2(ve.x), c1 = split2(ve.y), c2 = split2(ve.z), c3 = split2(ve.w);
        uint2 d0 = split2(vo.x), d1 = split2(vo.y), d2 = split2(vo.z), d3 = split2(vo.w);
        unsigned* kAp = planes[st & 1][0];
        unsigned* kBp = planes[st & 1][1];
        unsigned* vAp = planes[st & 1][2];
        unsigned* vBp = planes[st & 1][3];
        int wb = sp * 66 + c4 * 4;
        *(uint2*)&kAp[wb] = make_uint2((a0.x >> 16) | (b0.x & 0xffff0000u),
                                       (a1_.x >> 16) | (b1_.x & 0xffff0000u));
        *(uint2*)&kAp[wb + 2] = make_uint2((a2_.x >> 16) | (b2_.x & 0xffff0000u),
                                           (a3_.x >> 16) | (b3_.x & 0xffff0000u));
        *(uint2*)&kBp[wb] = make_uint2((a0.y >> 16) | (b0.y & 0xffff0000u),
                                       (a1_.y >> 16) | (b1_.y & 0xffff0000u));
        *(uint2*)&kBp[wb + 2] = make_uint2((a2_.y >> 16) | (b2_.y & 0xffff0000u),
                                           (a3_.y >> 16) | (b3_.y & 0xffff0000u));
        *(uint2*)&vAp[wb] = make_uint2((c0.x >> 16) | (d0.x & 0xffff0000u),
                                       (c1.x >> 16) | (d1.x & 0xffff0000u));
        *(uint2*)&vAp[wb + 2] = make_uint2((c2.x >> 16) | (d2.x & 0xffff0000u),
                                           (c3.x >> 16) | (d3.x & 0xffff0000u));
        *(uint2*)&vBp[wb] = make_uint2((c0.y >> 16) | (d0.y & 0xffff0000u),
                                       (c1.y >> 16) | (d1.y & 0xffff0000u));
        *(uint2*)&vBp[wb + 2] = make_uint2((c2.y >> 16) | (d2.y & 0xffff0000u),
                                           (c3.y >> 16) | (d3.y & 0xffff0000u));
        __syncthreads();   // writes of buf (st&1) visible; prior buf untouched
        // ---- MFMA: one K=32 step over these 32 s-rows
        U8 fa1, fa2;
#pragma unroll
        for (int jp = 0; jp < 4; ++jp) {
            int idx = (qd * 4 + jp) * 66 + wv * 16 + m;
            fa1.u[jp] = kAp[idx]; fa2.u[jp] = kBp[idx];
        }
#pragma unroll
        for (int e = 0; e < 4; ++e) {
            U8 fb1, fb2;
#pragma unroll
            for (int jp = 0; jp < 4; ++jp) {
                int idx = (qd * 4 + jp) * 66 + e * 16 + m;
                fb1.u[jp] = vAp[idx]; fb2.u[jp] = vBp[idx];
            }
            acc[e] = __builtin_amdgcn_mfma_f32_16x16x32_bf16(fa1.s, fb2.s, acc[e], 0, 0, 0);
            acc[e] = __builtin_amdgcn_mfma_f32_16x16x32_bf16(fa2.s, fb1.s, acc[e], 0, 0, 0);
            acc[e] = __builtin_amdgcn_mfma_f32_16x16x32_bf16(fa1.s, fb1.s, acc[e], 0, 0, 0);
        }
        if (st < 7) { ke = nke; ko = nko; ve = nve; vo = nvo; }
    }
    // epilogue: C/D layout col=lane&15, row=qd*4+reg; wave wv owns d-strip
    float* dst = &g_kvpart[((long)blockIdx.x * NH + nh) * 4096];
#pragma unroll
    for (int e = 0; e < 4; ++e)
#pragma unroll
        for (int r = 0; r < 4; ++r)
            dst[(wv * 16 + qd * 4 + r) * 64 + e * 16 + m] = acc[e][r];
    // knc partial: reduce over the 16 sp row-groups
    *(float4*)&kncred[sp * 64 + c4 * 4] = make_float4(knx, kny, knz, knw);
    esb[t] = esum;
    __syncthreads();
    if (t < 64) {
        float s = 0.f;
#pragma unroll
        for (int i = 0; i < 16; ++i) s += kncred[i * 64 + t];
        g_kncpart[(blockIdx.x * NH + nh) * 64 + t] = s;
    }
    for (int s2 = 128; s2; s2 >>= 1) {
        if (t < s2) esb[t] += esb[t + s2];
        __syncthreads();
    }
    if (t == 0) g_ssumpart[blockIdx.x * NH + nh] = esb[0];
}

// ---------------- k4b: reduce kv partials (scale), knc partials ----------------
__global__ __launch_bounds__(256) void k4b_reduce() {
    int nh = blockIdx.x, t = threadIdx.x;
    float ssum = 0.f;
#pragma unroll
    for (int c = 0; c < SCHUNKS; ++c) ssum += g_ssumpart[c * NH + nh];
    float scale = (float)L_ / ssum;
    int i4 = blockIdx.y * 256 + t;      // float4 index 0..1023
    float sx = 0.f, sy = 0.f, sz = 0.f, sw = 0.f;
#pragma unroll
    for (int c = 0; c < SCHUNKS; ++c) {
        float4 p = *(const float4*)&g_kvpart[((long)c * NH + nh) * 4096 + i4 * 4];
        sx += p.x; sy += p.y; sz += p.z; sw += p.w;
    }
    float4 o = {sx * scale, sy * scale, sz * scale, sw * scale};
    *(float4*)&g_kv[nh * 4096 + i4 * 4] = o;
    if (blockIdx.y == 0 && t < 64) {
        float s = 0.f;
#pragma unroll
        for (int c = 0; c < SCHUNKS; ++c) s += g_kncpart[(c * NH + nh) * 64 + t];
        g_knc[nh * 64 + t] = s;
    }
}

// ---------------- k5: inline coef + split2-bf16 MFMA out = sig(q)@kv * coef ---
__global__ __launch_bounds__(256, 4) void k5_out(const float* __restrict__ q,
                                                 float* __restrict__ out) {
    int nh = blockIdx.y, n = nh >> 4, h = nh & 15;
    int t = threadIdx.x, lane = t & 63, wv = t >> 6;
    __shared__ unsigned qA[32 * 66], qB[32 * 66], kvA[32 * 66], kvB[32 * 66];
    __shared__ float coef[64];
    int c4 = t & 15;
    long nbase = (long)n * NSTRIDE + (long)h * D_;
    int l0 = blockIdx.x * 64;
    float4 bk1 = *(const float4*)&g_ksum[nh * 64 + c4 * 4];
    float4 bk2 = *(const float4*)&g_knc[nh * 64 + c4 * 4];
    bk1.x += EPS; bk1.y += EPS; bk1.z += EPS; bk1.w += EPS;
    bk2.x += EPS; bk2.y += EPS; bk2.z += EPS; bk2.w += EPS;
    // hoist ALL staging loads (8 independent in flight)
    float4 xe[2], xo[2];
#pragma unroll
    for (int j = 0; j < 2; ++j) {
        int slot = t + j * 256;
        int dp = slot >> 4, cc = slot & 15;
        const float* kvr = &g_kv[nh * 4096 + (2 * dp) * 64 + cc * 4];
        xe[j] = *(const float4*)kvr;
        xo[j] = *(const float4*)(kvr + 64);
    }
    float4 xq[4];
#pragma unroll
    for (int j = 0; j < 4; ++j) {
        int r = (t >> 4) + j * 16;
        xq[j] = *(const float4*)&q[nbase + (long)(l0 + r) * HD + c4 * 4];
    }
    // stage kv (pair-packed over d)
#pragma unroll
    for (int j = 0; j < 2; ++j) {
        int slot = t + j * 256;
        int dp = slot >> 4, cc = slot & 15;
        uint2 e0 = split2(xe[j].x), e1 = split2(xe[j].y), e2 = split2(xe[j].z), e3 = split2(xe[j].w);
        uint2 o0 = split2(xo[j].x), o1 = split2(xo[j].y), o2 = split2(xo[j].z), o3 = split2(xo[j].w);
        int wb = dp * 66 + cc * 4;
        *(uint2*)&kvA[wb] = make_uint2((e0.x >> 16) | (o0.x & 0xffff0000u),
                                       (e1.x >> 16) | (o1.x & 0xffff0000u));
        *(uint2*)&kvA[wb + 2] = make_uint2((e2.x >> 16) | (o2.x & 0xffff0000u),
                                           (e3.x >> 16) | (o3.x & 0xffff0000u));
        *(uint2*)&kvB[wb] = make_uint2((e0.y >> 16) | (o0.y & 0xffff0000u),
                                       (e1.y >> 16) | (o1.y & 0xffff0000u));
        *(uint2*)&kvB[wb + 2] = make_uint2((e2.y >> 16) | (o2.y & 0xffff0000u),
                                           (e3.y >> 16) | (o3.y & 0xffff0000u));
    }
    // stage q (pair-packed over d, transposed to [dp][l]) + coef
#pragma unroll
    for (int j = 0; j < 4; ++j) {
        int r = (t >> 4) + j * 16;
        float4 s = sigm4(xq[j]);
        float p1 = (s.x + EPS) * bk1.x + (s.y + EPS) * bk1.y
                 + (s.z + EPS) * bk1.z + (s.w + EPS) * bk1.w;
        float p2 = (s.x + EPS) * bk2.x + (s.y + EPS) * bk2.y
                 + (s.z + EPS) * bk2.z + (s.w + EPS) * bk2.w;
        p1 = red16(p1); p2 = red16(p2);
        if (c4 == 0) coef[r] = sigm(p2) / p1;
        uint2 t0 = split2(s.x), t1 = split2(s.y), t2 = split2(s.z), t3 = split2(s.w);
        qA[(c4 * 2) * 66 + r]     = (t0.x >> 16) | (t1.x & 0xffff0000u);
        qB[(c4 * 2) * 66 + r]     = (t0.y >> 16) | (t1.y & 0xffff0000u);
        qA[(c4 * 2 + 1) * 66 + r] = (t2.x >> 16) | (t3.x & 0xffff0000u);
        qB[(c4 * 2 + 1) * 66 + r] = (t2.y >> 16) | (t3.y & 0xffff0000u);
    }
    __syncthreads();
    int m = lane & 15, qd = lane >> 4;
    f32x4 acc[4];
#pragma unroll
    for (int e = 0; e < 4; ++e) acc[e] = (f32x4){0.f, 0.f, 0.f, 0.f};
#pragma unroll
    for (int kk = 0; kk < 2; ++kk) {
        U8 fa1, fa2;
#pragma unroll
        for (int jp = 0; jp < 4; ++jp) {
            int idx = (kk * 16 + qd * 4 + jp) * 66 + wv * 16 + m;
            fa1.u[jp] = qA[idx]; fa2.u[jp] = qB[idx];
        }
#pragma unroll
        for (int e = 0; e < 4; ++e) {
            U8 fb1, fb2;
#pragma unroll
            for (int jp = 0; jp < 4; ++jp) {
                int idx = (kk * 16 + qd * 4 + jp) * 66 + e * 16 + m;
                fb1.u[jp] = kvA[idx]; fb2.u[jp] = kvB[idx];
            }
            acc[e] = __builtin_amdgcn_mfma_f32_16x16x32_bf16(fa1.s, fb2.s, acc[e], 0, 0, 0);
            acc[e] = __builtin_amdgcn_mfma_f32_16x16x32_bf16(fa2.s, fb1.s, acc[e], 0, 0, 0);
            acc[e] = __builtin_amdgcn_mfma_f32_16x16x32_bf16(fa1.s, fb1.s, acc[e], 0, 0, 0);
        }
    }
    // epilogue: l = l0 + wv*16 + qd*4 + r ; col = e*16 + m
#pragma unroll
    for (int e = 0; e < 4; ++e)
#pragma unroll
        for (int r = 0; r < 4; ++r) {
            int ll = wv * 16 + qd * 4 + r;
            out[nbase + (long)(l0 + ll) * HD + e * 16 + m] = acc[e][r] * coef[ll];
        }
}

extern "C" void kernel_launch(void* const* d_in, const int* in_sizes, int n_in,
                              void* d_out, int out_size, void* d_ws, size_t ws_size,
                              hipStream_t stream) {
    const float* q = (const float*)d_in[0];
    const float* k = (const float*)d_in[1];
    const float* v = (const float*)d_in[2];
    float* out = (float*)d_out;

    k0_zero<<<12, 256, 0, stream>>>();
    kA_ksum<<<2048, 256, 0, stream>>>(k);
    kB_q<<<2048, 256, 0, stream>>>(q);
    k4_kv<<<dim3(SCHUNKS, NH), 256, 0, stream>>>(k, v);
    k4b_reduce<<<dim3(NH, 4), 256, 0, stream>>>();
    k5_out<<<dim3(L_ / 64, NH), 256, 0, stream>>>(q, out);
}

// Round 6
// 272.013 us; speedup vs baseline: 2.2942x; 2.2942x over previous
//
#include <hip/hip_runtime.h>
#include <math.h>

#define EPS 1e-6f
constexpr int N_ = 4, L_ = 4096, H_ = 16, D_ = 64;
constexpr int NH = N_ * H_;             // 64
constexpr int HD = H_ * D_;             // 1024 floats per (n,l) row
constexpr long NSTRIDE = (long)L_ * HD;
constexpr int SCHUNKS = 16;             // 256 s-rows per kv chunk
constexpr int KSB = 2048;               // streaming blocks per tensor (8 rows each)

typedef __attribute__((ext_vector_type(8))) short short8;
typedef __attribute__((ext_vector_type(4))) float f32x4;

// Scratch device globals. All buffers fully written before read each call
// (graph-replay safe). NO global atomics anywhere (fabric-RMW serialization,
// measured round 5: 4.2M atomicAdds -> 295us).
__device__ float g_qsum[NH * D_];
__device__ float g_ksum[NH * D_];
__device__ float g_qnr[NH * D_];
__device__ float g_knc[NH * D_];
__device__ float g_kv[NH * D_ * D_];
__device__ float g_kvpart[(long)SCHUNKS * NH * D_ * D_];   // 16 MB
__device__ float g_kncpart[SCHUNKS * NH * D_];
__device__ float g_ssumpart[SCHUNKS * NH];
__device__ float g_partK[(long)KSB * 1024];                // 8 MB
__device__ float g_partQs[(long)KSB * 1024];               // 8 MB
__device__ float g_partQn[(long)KSB * 1024];               // 8 MB

__device__ __forceinline__ float sigm(float x) {
    return 1.0f / (1.0f + __expf(-x));
}
__device__ __forceinline__ float4 sigm4(float4 x) {
    float4 r;
    r.x = sigm(x.x); r.y = sigm(x.y); r.z = sigm(x.z); r.w = sigm(x.w);
    return r;
}
// 16-lane group sum via DPP (full-rate VALU, no DS-pipe traffic).
template <int CTRL>
__device__ __forceinline__ float dpp_add(float x) {
    int y = __builtin_amdgcn_update_dpp(0, __float_as_int(x), CTRL, 0xf, 0xf, true);
    return x + __int_as_float(y);
}
__device__ __forceinline__ float red16(float p) {
    p = dpp_add<0xB1>(p);    // quad_perm [1,0,3,2]  (xor 1)
    p = dpp_add<0x4E>(p);    // quad_perm [2,3,0,1]  (xor 2)
    p = dpp_add<0x141>(p);   // row_half_mirror
    p = dpp_add<0x140>(p);   // row_mirror
    return p;
}
// RNE round of fp32 bits to bf16, returned high-16-aligned
__device__ __forceinline__ unsigned rne_hi(unsigned xb) {
    return (xb + 0x7fffu + ((xb >> 16) & 1u)) & 0xffff0000u;
}
// split: x ~= h1 + h2 (each bf16), residual <= 2^-17 |x|
__device__ __forceinline__ uint2 split2(float x) {
    unsigned h1 = rne_hi(__float_as_uint(x));
    float r = x - __uint_as_float(h1);
    unsigned h2 = rne_hi(__float_as_uint(r));
    return make_uint2(h1, h2);
}
union U8 { unsigned u[4]; short8 s; };

// ---------------- kA: ksum partials; sched_barrier pins 8 loads in flight ----
__global__ __launch_bounds__(256, 8) void kA_ksum(const float* __restrict__ k) {
    int t = threadIdx.x;
    long g0 = (long)blockIdx.x * 8;
    const float* p = k + g0 * HD + t * 4;
    float4 x[8];
#pragma unroll
    for (int r = 0; r < 8; ++r) x[r] = *(const float4*)(p + (long)r * HD);
    __builtin_amdgcn_sched_barrier(0);   // loads may not sink past here
    float ax = 0.f, ay = 0.f, az = 0.f, aw = 0.f;
#pragma unroll
    for (int r = 0; r < 8; ++r) {
        float4 s = sigm4(x[r]);
        ax += s.x; ay += s.y; az += s.z; aw += s.w;
    }
    float4 o = {ax, ay, az, aw};
    *(float4*)&g_partK[((long)blockIdx.x << 10) + t * 4] = o;
}

// ---------------- kB: qsum AND qnr partials in ONE q pass ----------------
__global__ __launch_bounds__(256, 8) void kB_q(const float* __restrict__ q) {
    int t = threadIdx.x;
    long g0 = (long)blockIdx.x * 8;
    int n = (int)(g0 >> 12);            // 8 | 4096 so n constant per block
    float4 bv = *(const float4*)(g_ksum + n * 1024 + t * 4);
    bv.x += EPS; bv.y += EPS; bv.z += EPS; bv.w += EPS;
    const float* p = q + g0 * HD + t * 4;
    float4 x[8];
#pragma unroll
    for (int r = 0; r < 8; ++r) x[r] = *(const float4*)(p + (long)r * HD);
    __builtin_amdgcn_sched_barrier(0);
    float sx = 0.f, sy = 0.f, sz = 0.f, sw = 0.f;
    float nx = 0.f, ny = 0.f, nz = 0.f, nw = 0.f;
#pragma unroll
    for (int r = 0; r < 8; ++r) {
        float4 s = sigm4(x[r]);
        sx += s.x; sy += s.y; sz += s.z; sw += s.w;
        float pd = (s.x + EPS) * bv.x + (s.y + EPS) * bv.y
                 + (s.z + EPS) * bv.z + (s.w + EPS) * bv.w;
        pd = red16(pd);                 // full 64-d dot for this row's head
        float inv = 1.0f / pd;          // nr
        nx += s.x * inv; ny += s.y * inv; nz += s.z * inv; nw += s.w * inv;
    }
    float4 os = {sx, sy, sz, sw};
    float4 on = {nx, ny, nz, nw};
    *(float4*)&g_partQs[((long)blockIdx.x << 10) + t * 4] = os;
    *(float4*)&g_partQn[((long)blockIdx.x << 10) + t * 4] = on;
}

// ---------------- kred: parallel tree-reduce of streaming partials ----------
// mode 0: partK -> ksum, grid (128,1). mode 1: Qs->qsum, Qn->qnr, grid (128,2).
// Block j: n = j>>5, 32-col group (j&31)*32. 256 thr = 32 cols x 8 b-groups.
__global__ __launch_bounds__(256) void kred(int mode) {
    const float* src = (mode == 0) ? g_partK : (blockIdx.y ? g_partQn : g_partQs);
    float* dst = (mode == 0) ? g_ksum : (blockIdx.y ? g_qnr : g_qsum);
    int j = blockIdx.x;
    int n = j >> 5, colg = (j & 31) * 32;
    int t = threadIdx.x;
    int c = t & 31, bg = t >> 5;        // 8 b-groups of 64 rows each
    float s = 0.f;
#pragma unroll 8
    for (int i = 0; i < 64; ++i) {
        long row = (long)n * 512 + bg * 64 + i;
        s += src[(row << 10) + colg + c];
    }
    __shared__ float lds[256];
    lds[t] = s;
    __syncthreads();
    if (t < 128) lds[t] += lds[t + 128];
    __syncthreads();
    if (t < 64) lds[t] += lds[t + 64];
    __syncthreads();
    if (t < 32) dst[n * 1024 + colg + t] = lds[t] + lds[t + 32];
}

// ---------------- k4: fused nc+knc+cr+exp+ssum + split2-bf16 MFMA kv ---------
// Double-buffered LDS planes (1 barrier/step), prefetch issued at step top.
// LDS planes: u32 at [s-pair][col] = {lo16 = bf16(even s), hi16 = bf16(odd s)}
__global__ __launch_bounds__(256, 4) void k4_kv(const float* __restrict__ k,
                                                const float* __restrict__ v) {
    int nh = blockIdx.y, n = nh >> 4, h = nh & 15;
    int t = threadIdx.x, lane = t & 63, wv = t >> 6;
    __shared__ unsigned planes[2][4][16 * 66];   // [buf][kA,kB,vA,vB]
    __shared__ float kncred[16 * 64];
    __shared__ float esb[256];
    int sp = t >> 4, c4 = t & 15;
    long nbase = (long)n * NSTRIDE + (long)h * D_;
    int s0blk = blockIdx.x * 256;
    float4 qn = *(const float4*)&g_qnr[nh * 64 + c4 * 4];
    qn.x += EPS; qn.y += EPS; qn.z += EPS; qn.w += EPS;
    float4 qs = *(const float4*)&g_qsum[nh * 64 + c4 * 4];
    qs.x += EPS; qs.y += EPS; qs.z += EPS; qs.w += EPS;

    f32x4 acc[4];
#pragma unroll
    for (int e = 0; e < 4; ++e) acc[e] = (f32x4){0.f, 0.f, 0.f, 0.f};
    int m = lane & 15, qd = lane >> 4;
    float esum = 0.f;
    float knx = 0.f, kny = 0.f, knz = 0.f, knw = 0.f;

    float4 ke, ko, ve, vo;
    {
        long gb = nbase + (long)(s0blk + 2 * sp) * HD + c4 * 4;
        ke = *(const float4*)&k[gb]; ko = *(const float4*)&k[gb + HD];
        ve = *(const float4*)&v[gb]; vo = *(const float4*)&v[gb + HD];
    }
    for (int st = 0; st < 8; ++st) {
        // ---- issue next subtile's loads FIRST; pin with sched_barrier
        float4 nke, nko, nve, nvo;
        if (st < 7) {
            long gb = nbase + (long)(s0blk + (st + 1) * 32 + 2 * sp) * HD + c4 * 4;
            nke = *(const float4*)&k[gb]; nko = *(const float4*)&k[gb + HD];
            nve = *(const float4*)&v[gb]; nvo = *(const float4*)&v[gb + HD];
            __builtin_amdgcn_sched_barrier(0);
        }
        // ---- sigm + nc/cr dots (DPP) + exp + knc + scale + pack
        float4 se = sigm4(ke), so = sigm4(ko);
        float pde = (se.x + EPS) * qn.x + (se.y + EPS) * qn.y
                  + (se.z + EPS) * qn.z + (se.w + EPS) * qn.w;
        float pdo = (so.x + EPS) * qn.x + (so.y + EPS) * qn.y
                  + (so.z + EPS) * qn.z + (so.w + EPS) * qn.w;
        float pne = (se.x + EPS) * qs.x + (se.y + EPS) * qs.y
                  + (se.z + EPS) * qs.z + (se.w + EPS) * qs.w;
        float pno = (so.x + EPS) * qs.x + (so.y + EPS) * qs.y
                  + (so.z + EPS) * qs.z + (so.w + EPS) * qs.w;
        pde = red16(pde); pdo = red16(pdo);
        pne = red16(pne); pno = red16(pno);
        float ee = __expf(pde), eo = __expf(pdo);
        if (c4 == 0) esum += ee + eo;
        float nce = 1.0f / pne, nco = 1.0f / pno;
        knx += se.x * nce + so.x * nco;
        kny += se.y * nce + so.y * nco;
        knz += se.z * nce + so.z * nco;
        knw += se.w * nce + so.w * nco;
        se.x *= ee; se.y *= ee; se.z *= ee; se.w *= ee;
        so.x *= eo; so.y *= eo; so.z *= eo; so.w *= eo;
        uint2 a0 = split2(se.x), a1_ = split2(se.y), a2_ = split2(se.z), a3_ = split2(se.w);
        uint2 b0 = split2(so.x), b1_ = split2(so.y), b2_ = split2(so.z), b3_ = split2(so.w);
        uint2 c0 = split2(ve.x), c1 = split2(ve.y), c2 = split2(ve.z), c3 = split2(ve.w);
        uint2 d0 = split2(vo.x), d1 = split2(vo.y), d2 = split2(vo.z), d3 = split2(vo.w);
        unsigned* kAp = planes[st & 1][0];
        unsigned* kBp = planes[st & 1][1];
        unsigned* vAp = planes[st & 1][2];
        unsigned* vBp = planes[st & 1][3];
        int wb = sp * 66 + c4 * 4;
        *(uint2*)&kAp[wb] = make_uint2((a0.x >> 16) | (b0.x & 0xffff0000u),
                                       (a1_.x >> 16) | (b1_.x & 0xffff0000u));
        *(uint2*)&kAp[wb + 2] = make_uint2((a2_.x >> 16) | (b2_.x & 0xffff0000u),
                                           (a3_.x >> 16) | (b3_.x & 0xffff0000u));
        *(uint2*)&kBp[wb] = make_uint2((a0.y >> 16) | (b0.y & 0xffff0000u),
                                       (a1_.y >> 16) | (b1_.y & 0xffff0000u));
        *(uint2*)&kBp[wb + 2] = make_uint2((a2_.y >> 16) | (b2_.y & 0xffff0000u),
                                           (a3_.y >> 16) | (b3_.y & 0xffff0000u));
        *(uint2*)&vAp[wb] = make_uint2((c0.x >> 16) | (d0.x & 0xffff0000u),
                                       (c1.x >> 16) | (d1.x & 0xffff0000u));
        *(uint2*)&vAp[wb + 2] = make_uint2((c2.x >> 16) | (d2.x & 0xffff0000u),
                                           (c3.x >> 16) | (d3.x & 0xffff0000u));
        *(uint2*)&vBp[wb] = make_uint2((c0.y >> 16) | (d0.y & 0xffff0000u),
                                       (c1.y >> 16) | (d1.y & 0xffff0000u));
        *(uint2*)&vBp[wb + 2] = make_uint2((c2.y >> 16) | (d2.y & 0xffff0000u),
                                           (c3.y >> 16) | (d3.y & 0xffff0000u));
        __syncthreads();   // writes of buf (st&1) visible; other buf untouched
        // ---- MFMA: one K=32 step over these 32 s-rows
        U8 fa1, fa2;
#pragma unroll
        for (int jp = 0; jp < 4; ++jp) {
            int idx = (qd * 4 + jp) * 66 + wv * 16 + m;
            fa1.u[jp] = kAp[idx]; fa2.u[jp] = kBp[idx];
        }
#pragma unroll
        for (int e = 0; e < 4; ++e) {
            U8 fb1, fb2;
#pragma unroll
            for (int jp = 0; jp < 4; ++jp) {
                int idx = (qd * 4 + jp) * 66 + e * 16 + m;
                fb1.u[jp] = vAp[idx]; fb2.u[jp] = vBp[idx];
            }
            acc[e] = __builtin_amdgcn_mfma_f32_16x16x32_bf16(fa1.s, fb2.s, acc[e], 0, 0, 0);
            acc[e] = __builtin_amdgcn_mfma_f32_16x16x32_bf16(fa2.s, fb1.s, acc[e], 0, 0, 0);
            acc[e] = __builtin_amdgcn_mfma_f32_16x16x32_bf16(fa1.s, fb1.s, acc[e], 0, 0, 0);
        }
        if (st < 7) { ke = nke; ko = nko; ve = nve; vo = nvo; }
    }
    // epilogue: C/D layout col=lane&15, row=qd*4+reg; wave wv owns d-strip
    float* dst = &g_kvpart[((long)blockIdx.x * NH + nh) * 4096];
#pragma unroll
    for (int e = 0; e < 4; ++e)
#pragma unroll
        for (int r = 0; r < 4; ++r)
            dst[(wv * 16 + qd * 4 + r) * 64 + e * 16 + m] = acc[e][r];
    // knc partial: reduce over the 16 sp row-groups
    *(float4*)&kncred[sp * 64 + c4 * 4] = make_float4(knx, kny, knz, knw);
    esb[t] = esum;
    __syncthreads();
    if (t < 64) {
        float s = 0.f;
#pragma unroll
        for (int i = 0; i < 16; ++i) s += kncred[i * 64 + t];
        g_kncpart[(blockIdx.x * NH + nh) * 64 + t] = s;
    }
    for (int s2 = 128; s2; s2 >>= 1) {
        if (t < s2) esb[t] += esb[t + s2];
        __syncthreads();
    }
    if (t == 0) g_ssumpart[blockIdx.x * NH + nh] = esb[0];
}

// ---------------- k4b: reduce kv partials (scale), knc partials ----------------
__global__ __launch_bounds__(256) void k4b_reduce() {
    int nh = blockIdx.x, t = threadIdx.x;
    float ssum = 0.f;
#pragma unroll
    for (int c = 0; c < SCHUNKS; ++c) ssum += g_ssumpart[c * NH + nh];
    float scale = (float)L_ / ssum;
    int i4 = blockIdx.y * 256 + t;      // float4 index 0..1023
    float sx = 0.f, sy = 0.f, sz = 0.f, sw = 0.f;
#pragma unroll
    for (int c = 0; c < SCHUNKS; ++c) {
        float4 p = *(const float4*)&g_kvpart[((long)c * NH + nh) * 4096 + i4 * 4];
        sx += p.x; sy += p.y; sz += p.z; sw += p.w;
    }
    float4 o = {sx * scale, sy * scale, sz * scale, sw * scale};
    *(float4*)&g_kv[nh * 4096 + i4 * 4] = o;
    if (blockIdx.y == 0 && t < 64) {
        float s = 0.f;
#pragma unroll
        for (int c = 0; c < SCHUNKS; ++c) s += g_kncpart[(c * NH + nh) * 64 + t];
        g_knc[nh * 64 + t] = s;
    }
}

// ---------------- k5: inline coef + split2-bf16 MFMA out = sig(q)@kv * coef ---
__global__ __launch_bounds__(256, 4) void k5_out(const float* __restrict__ q,
                                                 float* __restrict__ out) {
    int nh = blockIdx.y, n = nh >> 4, h = nh & 15;
    int t = threadIdx.x, lane = t & 63, wv = t >> 6;
    __shared__ unsigned qA[32 * 66], qB[32 * 66], kvA[32 * 66], kvB[32 * 66];
    __shared__ float coef[64];
    int c4 = t & 15;
    long nbase = (long)n * NSTRIDE + (long)h * D_;
    int l0 = blockIdx.x * 64;
    float4 bk1 = *(const float4*)&g_ksum[nh * 64 + c4 * 4];
    float4 bk2 = *(const float4*)&g_knc[nh * 64 + c4 * 4];
    bk1.x += EPS; bk1.y += EPS; bk1.z += EPS; bk1.w += EPS;
    bk2.x += EPS; bk2.y += EPS; bk2.z += EPS; bk2.w += EPS;
    // hoist ALL staging loads; sched_barrier keeps them in flight together
    float4 xe[2], xo[2];
#pragma unroll
    for (int j = 0; j < 2; ++j) {
        int slot = t + j * 256;
        int dp = slot >> 4, cc = slot & 15;
        const float* kvr = &g_kv[nh * 4096 + (2 * dp) * 64 + cc * 4];
        xe[j] = *(const float4*)kvr;
        xo[j] = *(const float4*)(kvr + 64);
    }
    float4 xq[4];
#pragma unroll
    for (int j = 0; j < 4; ++j) {
        int r = (t >> 4) + j * 16;
        xq[j] = *(const float4*)&q[nbase + (long)(l0 + r) * HD + c4 * 4];
    }
    __builtin_amdgcn_sched_barrier(0);
    // stage kv (pair-packed over d)
#pragma unroll
    for (int j = 0; j < 2; ++j) {
        int slot = t + j * 256;
        int dp = slot >> 4, cc = slot & 15;
        uint2 e0 = split2(xe[j].x), e1 = split2(xe[j].y), e2 = split2(xe[j].z), e3 = split2(xe[j].w);
        uint2 o0 = split2(xo[j].x), o1 = split2(xo[j].y), o2 = split2(xo[j].z), o3 = split2(xo[j].w);
        int wb = dp * 66 + cc * 4;
        *(uint2*)&kvA[wb] = make_uint2((e0.x >> 16) | (o0.x & 0xffff0000u),
                                       (e1.x >> 16) | (o1.x & 0xffff0000u));
        *(uint2*)&kvA[wb + 2] = make_uint2((e2.x >> 16) | (o2.x & 0xffff0000u),
                                           (e3.x >> 16) | (o3.x & 0xffff0000u));
        *(uint2*)&kvB[wb] = make_uint2((e0.y >> 16) | (o0.y & 0xffff0000u),
                                       (e1.y >> 16) | (o1.y & 0xffff0000u));
        *(uint2*)&kvB[wb + 2] = make_uint2((e2.y >> 16) | (o2.y & 0xffff0000u),
                                           (e3.y >> 16) | (o3.y & 0xffff0000u));
    }
    // stage q (pair-packed over d, transposed to [dp][l]) + coef
#pragma unroll
    for (int j = 0; j < 4; ++j) {
        int r = (t >> 4) + j * 16;
        float4 s = sigm4(xq[j]);
        float p1 = (s.x + EPS) * bk1.x + (s.y + EPS) * bk1.y
                 + (s.z + EPS) * bk1.z + (s.w + EPS) * bk1.w;
        float p2 = (s.x + EPS) * bk2.x + (s.y + EPS) * bk2.y
                 + (s.z + EPS) * bk2.z + (s.w + EPS) * bk2.w;
        p1 = red16(p1); p2 = red16(p2);
        if (c4 == 0) coef[r] = sigm(p2) / p1;
        uint2 t0 = split2(s.x), t1 = split2(s.y), t2 = split2(s.z), t3 = split2(s.w);
        qA[(c4 * 2) * 66 + r]     = (t0.x >> 16) | (t1.x & 0xffff0000u);
        qB[(c4 * 2) * 66 + r]     = (t0.y >> 16) | (t1.y & 0xffff0000u);
        qA[(c4 * 2 + 1) * 66 + r] = (t2.x >> 16) | (t3.x & 0xffff0000u);
        qB[(c4 * 2 + 1) * 66 + r] = (t2.y >> 16) | (t3.y & 0xffff0000u);
    }
    __syncthreads();
    int m = lane & 15, qd = lane >> 4;
    f32x4 acc[4];
#pragma unroll
    for (int e = 0; e < 4; ++e) acc[e] = (f32x4){0.f, 0.f, 0.f, 0.f};
#pragma unroll
    for (int kk = 0; kk < 2; ++kk) {
        U8 fa1, fa2;
#pragma unroll
        for (int jp = 0; jp < 4; ++jp) {
            int idx = (kk * 16 + qd * 4 + jp) * 66 + wv * 16 + m;
            fa1.u[jp] = qA[idx]; fa2.u[jp] = qB[idx];
        }
#pragma unroll
        for (int e = 0; e < 4; ++e) {
            U8 fb1, fb2;
#pragma unroll
            for (int jp = 0; jp < 4; ++jp) {
                int idx = (kk * 16 + qd * 4 + jp) * 66 + e * 16 + m;
                fb1.u[jp] = kvA[idx]; fb2.u[jp] = kvB[idx];
            }
            acc[e] = __builtin_amdgcn_mfma_f32_16x16x32_bf16(fa1.s, fb2.s, acc[e], 0, 0, 0);
            acc[e] = __builtin_amdgcn_mfma_f32_16x16x32_bf16(fa2.s, fb1.s, acc[e], 0, 0, 0);
            acc[e] = __builtin_amdgcn_mfma_f32_16x16x32_bf16(fa1.s, fb1.s, acc[e], 0, 0, 0);
        }
    }
    // epilogue: l = l0 + wv*16 + qd*4 + r ; col = e*16 + m
#pragma unroll
    for (int e = 0; e < 4; ++e)
#pragma unroll
        for (int r = 0; r < 4; ++r) {
            int ll = wv * 16 + qd * 4 + r;
            out[nbase + (long)(l0 + ll) * HD + e * 16 + m] = acc[e][r] * coef[ll];
        }
}

extern "C" void kernel_launch(void* const* d_in, const int* in_sizes, int n_in,
                              void* d_out, int out_size, void* d_ws, size_t ws_size,
                              hipStream_t stream) {
    const float* q = (const float*)d_in[0];
    const float* k = (const float*)d_in[1];
    const float* v = (const float*)d_in[2];
    float* out = (float*)d_out;

    kA_ksum<<<KSB, 256, 0, stream>>>(k);
    kred<<<dim3(128, 1), 256, 0, stream>>>(0);
    kB_q<<<KSB, 256, 0, stream>>>(q);
    kred<<<dim3(128, 2), 256, 0, stream>>>(1);
    k4_kv<<<dim3(SCHUNKS, NH), 256, 0, stream>>>(k, v);
    k4b_reduce<<<dim3(NH, 4), 256, 0, stream>>>();
    k5_out<<<dim3(L_ / 64, NH), 256, 0, stream>>>(q, out);
}